// Round 4
// baseline (11060.135 us; speedup 1.0000x reference)
//
#include <hip/hip_runtime.h>

// Problem constants (B=4, N=2048, C=256, H=8, D=32, keep = int(2048*0.3) = 614)
#define BDIM 4
#define NSEQ 2048
#define CDIM 256
#define NHEADS 8
#define QB 8                     // query rows per block (2 per wave)
#define NKEEP 614                // int(2048 * (1.0 - 0.7))
#define ATTN_SCALE 0.17677669529663688f  // 32^-0.5

// -------------------------------------------------------------------------
// GEMM: C[M][Nt] = A[M][K] @ W[Nt][K]^T + bias[Nt]   (unchanged, validated)
// -------------------------------------------------------------------------
__global__ __launch_bounds__(256) void gemm_nt_bias(
    const float* __restrict__ A, const float* __restrict__ W,
    const float* __restrict__ bias, float* __restrict__ C,
    int M, int Nt, int K)
{
    __shared__ __align__(16) float As[32][68];
    __shared__ __align__(16) float Ws[32][68];
    const int tid = threadIdx.x;
    const int bm = blockIdx.x * 64;
    const int bn = blockIdx.y * 64;
    const int tm = tid >> 4;
    const int tn = tid & 15;
    const int lr = tid >> 2;
    const int lq = tid & 3;
    const float* Ap = A + (size_t)(bm + lr) * K + lq * 8;
    const float* Wp = W + (size_t)(bn + lr) * K + lq * 8;
    float acc[4][4] = {};

    for (int k0 = 0; k0 < K; k0 += 32) {
        float4 a0 = *(const float4*)(Ap + k0);
        float4 a1 = *(const float4*)(Ap + k0 + 4);
        float4 w0 = *(const float4*)(Wp + k0);
        float4 w1 = *(const float4*)(Wp + k0 + 4);
        __syncthreads();
        const int kq = lq * 8;
        As[kq+0][lr]=a0.x; As[kq+1][lr]=a0.y; As[kq+2][lr]=a0.z; As[kq+3][lr]=a0.w;
        As[kq+4][lr]=a1.x; As[kq+5][lr]=a1.y; As[kq+6][lr]=a1.z; As[kq+7][lr]=a1.w;
        Ws[kq+0][lr]=w0.x; Ws[kq+1][lr]=w0.y; Ws[kq+2][lr]=w0.z; Ws[kq+3][lr]=w0.w;
        Ws[kq+4][lr]=w1.x; Ws[kq+5][lr]=w1.y; Ws[kq+6][lr]=w1.z; Ws[kq+7][lr]=w1.w;
        __syncthreads();
        #pragma unroll
        for (int k = 0; k < 32; ++k) {
            float4 av = *(const float4*)&As[k][tm*4];
            float4 wv = *(const float4*)&Ws[k][tn*4];
            acc[0][0] += av.x*wv.x; acc[0][1] += av.x*wv.y; acc[0][2] += av.x*wv.z; acc[0][3] += av.x*wv.w;
            acc[1][0] += av.y*wv.x; acc[1][1] += av.y*wv.y; acc[1][2] += av.y*wv.z; acc[1][3] += av.y*wv.w;
            acc[2][0] += av.z*wv.x; acc[2][1] += av.z*wv.y; acc[2][2] += av.z*wv.z; acc[2][3] += av.z*wv.w;
            acc[3][0] += av.w*wv.x; acc[3][1] += av.w*wv.y; acc[3][2] += av.w*wv.z; acc[3][3] += av.w*wv.w;
        }
    }
    float4 bb = *(const float4*)(bias + bn + tn*4);
    #pragma unroll
    for (int i = 0; i < 4; ++i) {
        float4 o;
        o.x = acc[i][0] + bb.x;
        o.y = acc[i][1] + bb.y;
        o.z = acc[i][2] + bb.z;
        o.w = acc[i][3] + bb.w;
        *(float4*)(C + (size_t)(bm + tm*4 + i) * Nt + bn + tn*4) = o;
    }
}

// -------------------------------------------------------------------------
// Fused sparse attention, register-resident scores, Q in LDS (low VGPR).
// Wave w owns query rows 2w, 2w+1. Thread (w, l) owns columns j = 64*t + l.
// Ring discipline per iteration: vmcnt(tile t landed) -> barrier -> stage(t+2)
// -> compute(t). Barrier precedes the overwrite of buf[(t-1)%3]: race-free.
// -------------------------------------------------------------------------
__device__ __forceinline__ unsigned int f2key(float f) {
    unsigned int u = __float_as_uint(f);
    return (u & 0x80000000u) ? ~u : (u | 0x80000000u);  // monotone order-preserving
}

typedef __attribute__((address_space(1))) const void gas_void;
typedef __attribute__((address_space(3))) void las_void;

__device__ __forceinline__ void gload_lds16(const float* g, float4* l) {
    __builtin_amdgcn_global_load_lds((gas_void*)g, (las_void*)l, 16, 0, 0);
}

// stage 64 rows x 32 floats (global row stride 768 floats) into dst4[512]
// LDS float4 slot = row*8 + ((slot&7) ^ (row&7)) via pre-swizzled source.
__device__ __forceinline__ void stage64(const float* __restrict__ g, float4* dst4, int tid) {
    const int s0 = tid, s1 = tid + 256;
    const int r0 = s0 >> 3, c0 = (s0 & 7) ^ (r0 & 7);
    const int r1 = s1 >> 3, c1 = (s1 & 7) ^ (r1 & 7);
    gload_lds16(g + (size_t)r0 * 768 + c0 * 4, dst4 + s0);
    gload_lds16(g + (size_t)r1 * 768 + c1 * 4, dst4 + s1);
}

// raw barrier: drain LDS ops, do NOT drain vmcnt (keeps prefetch in flight)
#define RBAR() do { asm volatile("s_waitcnt lgkmcnt(0)" ::: "memory"); \
                    __builtin_amdgcn_s_barrier();                      \
                    asm volatile("" ::: "memory"); } while (0)

__global__ __launch_bounds__(256) void sparse_attn(
    const float* __restrict__ qkv, float* __restrict__ aout)
{
    __shared__ __align__(16) float4 kbuf[3][512];    // 24 KB tile ring (K then V)
    __shared__ unsigned int hist[QB * 256];           // 8 KB
    __shared__ __align__(16) float q_sh[QB][32];      // 1 KB, pre-scaled Q
    __shared__ unsigned int prefS[QB];
    __shared__ int remS[QB];
    __shared__ float thrS[QB];

    const int tid  = threadIdx.x;
    const int l    = tid & 63;        // lane in wave
    const int w    = tid >> 6;        // wave id 0..3
    const int li   = l & 31;
    const int half = l >> 5;          // 0 -> row 2w, 1 -> row 2w+1
    const int myrow = 2 * w + half;
    const int swz  = l & 7;

    const int blk = blockIdx.x;
    const int nb  = NSEQ / QB;        // 256 q-blocks per (b,h)
    const int bh  = blk / nb;
    const int qb  = blk % nb;
    const int b   = bh / NHEADS;
    const int h   = bh % NHEADS;
    const int n0  = qb * QB;

    const float* base = qkv + (size_t)b * NSEQ * 768;
    const float* gq = base + (size_t)n0 * 768 + h * 32;
    const float* gk = base + 256 + h * 32;
    const float* gv = base + 512 + h * 32;

    // --- Q (pre-scaled) into LDS: 1 KB, read as wave-uniform broadcasts ---
    {
        int r = tid >> 5, d = tid & 31;
        q_sh[r][d] = gq[(size_t)r * 768 + d] * ATTN_SCALE;
    }
    if (tid < QB) { prefS[tid] = 0u; remS[tid] = NKEEP; }

    float sA[32], sB[32];

    // ---- Phase B: scores (K tiles, triple-buffered, counted vmcnt) ----
    stage64(gk, &kbuf[0][0], tid);
    stage64(gk + (size_t)64 * 768, &kbuf[1][0], tid);
    #pragma unroll
    for (int t = 0; t < 32; ++t) {
        if (t + 1 < 32) asm volatile("s_waitcnt vmcnt(2)" ::: "memory");
        else            asm volatile("s_waitcnt vmcnt(0)" ::: "memory");
        RBAR();   // all waves done with tile t-1 reads; safe to overwrite its buffer
        if (t + 2 < 32) stage64(gk + (size_t)(t + 2) * 64 * 768, &kbuf[(t + 2) % 3][0], tid);
        const float4* kb = &kbuf[t % 3][0];
        float a0e = 0.f, a0o = 0.f, a1e = 0.f, a1o = 0.f;
        #pragma unroll
        for (int cc = 0; cc < 8; ++cc) {
            float4 kv  = kb[l * 8 + (cc ^ swz)];
            float4 qv0 = *(const float4*)&q_sh[2 * w][4 * cc];
            float4 qv1 = *(const float4*)&q_sh[2 * w + 1][4 * cc];
            a0e = fmaf(qv0.x, kv.x, a0e); a0o = fmaf(qv0.y, kv.y, a0o);
            a0e = fmaf(qv0.z, kv.z, a0e); a0o = fmaf(qv0.w, kv.w, a0o);
            a1e = fmaf(qv1.x, kv.x, a1e); a1o = fmaf(qv1.y, kv.y, a1o);
            a1e = fmaf(qv1.z, kv.z, a1e); a1o = fmaf(qv1.w, kv.w, a1o);
        }
        sA[t] = a0e + a0o;
        sB[t] = a1e + a1o;
    }

    // All waves done reading K tiles after this barrier -> start V tiles 0,1;
    // they fly across the whole select/softmax phase (RBAR never drains vmcnt).
    RBAR();
    stage64(gv, &kbuf[0][0], tid);
    stage64(gv + (size_t)64 * 768, &kbuf[1][0], tid);

    // ---- Phase C: exact 614th-largest per row, radix select on f2key ----
    #pragma unroll
    for (int pass = 3; pass >= 0; --pass) {
        #pragma unroll
        for (int i = 0; i < 8; ++i) hist[tid + 256 * i] = 0u;
        RBAR();
        const int sh = pass * 8;
        const unsigned int hmsk = (pass == 3) ? 0u : (0xFFFFFFFFu << (sh + 8));
        const unsigned int pr0 = prefS[2 * w];
        const unsigned int pr1 = prefS[2 * w + 1];
        #pragma unroll
        for (int t = 0; t < 32; ++t) {
            unsigned int k0 = f2key(sA[t]);
            if ((k0 & hmsk) == pr0) atomicAdd(&hist[(2 * w) * 256 + ((k0 >> sh) & 255u)], 1u);
            unsigned int k1 = f2key(sB[t]);
            if ((k1 & hmsk) == pr1) atomicAdd(&hist[(2 * w + 1) * 256 + ((k1 >> sh) & 255u)], 1u);
        }
        RBAR();
        // suffix scan: half-wave (32 lanes) per row, lane li owns bins [8li, 8li+8)
        unsigned int cnt[8];
        unsigned int part = 0u;
        #pragma unroll
        for (int i = 0; i < 8; ++i) { cnt[i] = hist[myrow * 256 + li * 8 + i]; part += cnt[i]; }
        unsigned int suf = part;
        #pragma unroll
        for (int dlt = 1; dlt < 32; dlt <<= 1) {
            unsigned int v = __shfl_down(suf, dlt, 32);
            if (li + dlt < 32) suf += v;
        }
        unsigned int run = suf - part;     // elems in bins owned by lanes > li
        const int remv = remS[myrow];
        const unsigned int prm = half ? pr1 : pr0;
        #pragma unroll
        for (int i = 7; i >= 0; --i) {
            if ((int)run < remv && remv <= (int)(run + cnt[i])) {
                remS[myrow]  = remv - (int)run;
                prefS[myrow] = prm | ((unsigned int)(li * 8 + i) << sh);
            }
            run += cnt[i];
        }
        RBAR();
    }
    if (tid < QB) {
        unsigned int key = prefS[tid];
        unsigned int u = (key & 0x80000000u) ? (key & 0x7FFFFFFFu) : ~key;
        thrS[tid] = __uint_as_float(u);
    }
    RBAR();

    // ---- Phase D: masked softmax on register scores ----
    const float thr0 = thrS[2 * w], thr1 = thrS[2 * w + 1];
    float m0 = 0.f, m1 = 0.f;   // >=1434 masked zeros always present
    #pragma unroll
    for (int t = 0; t < 32; ++t) {
        sA[t] = (sA[t] >= thr0) ? sA[t] : 0.f;
        sB[t] = (sB[t] >= thr1) ? sB[t] : 0.f;
        m0 = fmaxf(m0, sA[t]); m1 = fmaxf(m1, sB[t]);
    }
    #pragma unroll
    for (int d2 = 32; d2 >= 1; d2 >>= 1) {
        m0 = fmaxf(m0, __shfl_xor(m0, d2));
        m1 = fmaxf(m1, __shfl_xor(m1, d2));
    }
    float Z0 = 0.f, Z1 = 0.f;
    #pragma unroll
    for (int t = 0; t < 32; ++t) {
        float p0 = __expf(sA[t] - m0); sA[t] = p0; Z0 += p0;
        float p1 = __expf(sB[t] - m1); sB[t] = p1; Z1 += p1;
    }
    #pragma unroll
    for (int d2 = 32; d2 >= 1; d2 >>= 1) { Z0 += __shfl_xor(Z0, d2); Z1 += __shfl_xor(Z1, d2); }

    // ---- Phase E: PV (V tiles, same ring; tiles 0,1 already in flight) ----
    float oA[32], oB[32];
    #pragma unroll
    for (int d = 0; d < 32; ++d) { oA[d] = 0.f; oB[d] = 0.f; }
    #pragma unroll
    for (int t = 0; t < 32; ++t) {
        if (t + 1 < 32) asm volatile("s_waitcnt vmcnt(2)" ::: "memory");
        else            asm volatile("s_waitcnt vmcnt(0)" ::: "memory");
        RBAR();   // all waves done with V tile t-1 reads; safe to overwrite
        if (t + 2 < 32) stage64(gv + (size_t)(t + 2) * 64 * 768, &kbuf[(t + 2) % 3][0], tid);
        const float4* vb = &kbuf[t % 3][0];
        const float pa = sA[t], pb = sB[t];
        #pragma unroll
        for (int cc = 0; cc < 8; ++cc) {
            float4 vv = vb[l * 8 + (cc ^ swz)];
            oA[4*cc+0] = fmaf(pa, vv.x, oA[4*cc+0]); oA[4*cc+1] = fmaf(pa, vv.y, oA[4*cc+1]);
            oA[4*cc+2] = fmaf(pa, vv.z, oA[4*cc+2]); oA[4*cc+3] = fmaf(pa, vv.w, oA[4*cc+3]);
            oB[4*cc+0] = fmaf(pb, vv.x, oB[4*cc+0]); oB[4*cc+1] = fmaf(pb, vv.y, oB[4*cc+1]);
            oB[4*cc+2] = fmaf(pb, vv.z, oB[4*cc+2]); oB[4*cc+3] = fmaf(pb, vv.w, oB[4*cc+3]);
        }
    }

    // ---- cross-lane reduce: fold rows to halves, then width-32 butterfly ----
    float oC[32];
    #pragma unroll
    for (int d = 0; d < 32; ++d) {
        float ta = oA[d] + __shfl_xor(oA[d], 32);
        float tb = oB[d] + __shfl_xor(oB[d], 32);
        oC[d] = half ? tb : ta;
    }
    #pragma unroll
    for (int d2 = 16; d2 >= 1; d2 >>= 1) {
        #pragma unroll
        for (int d = 0; d < 32; ++d) oC[d] += __shfl_xor(oC[d], d2);
    }
    // lane (half, li) writes out[row=2w+half][d=li]; static-index extraction
    float val = 0.f;
    #pragma unroll
    for (int dd = 0; dd < 32; ++dd) if (li == dd) val = oC[dd];
    val /= (half ? Z1 : Z0);
    aout[((size_t)b * NSEQ + n0 + myrow) * CDIM + h * 32 + li] = val;
}

// -------------------------------------------------------------------------
extern "C" void kernel_launch(void* const* d_in, const int* in_sizes, int n_in,
                              void* d_out, int out_size, void* d_ws, size_t ws_size,
                              hipStream_t stream) {
    (void)in_sizes; (void)n_in; (void)out_size; (void)ws_size;
    const float* x      = (const float*)d_in[0];
    const float* w_qkv  = (const float*)d_in[1];
    const float* b_qkv  = (const float*)d_in[2];
    const float* w_proj = (const float*)d_in[3];
    const float* b_proj = (const float*)d_in[4];
    float* out = (float*)d_out;

    const int M = BDIM * NSEQ;  // 8192
    float* qkv_ws  = (float*)d_ws;                       // 25.2 MB
    float* attn_ws = qkv_ws + (size_t)M * 768;           // 8.4 MB

    // 1) QKV GEMM -> [B][N][3][H][D]
    dim3 g1(M / 64, 768 / 64);
    gemm_nt_bias<<<g1, 256, 0, stream>>>(x, w_qkv, b_qkv, qkv_ws, M, 768, 256);

    // 2) fused sparse attention -> [B][N][C]
    sparse_attn<<<BDIM * NHEADS * NSEQ / QB, 256, 0, stream>>>(qkv_ws, attn_ws);

    // 3) projection GEMM -> d_out
    dim3 g2(M / 64, 256 / 64);
    gemm_nt_bias<<<g2, 256, 0, stream>>>(attn_ws, w_proj, b_proj, out, M, 256, 256);
}

// Round 5
// 1376.460 us; speedup vs baseline: 8.0352x; 8.0352x over previous
//
#include <hip/hip_runtime.h>

// Problem constants (B=4, N=2048, C=256, H=8, D=32, keep = int(2048*0.3) = 614)
#define BDIM 4
#define NSEQ 2048
#define CDIM 256
#define NHEADS 8
#define QB 4                     // query rows per block (1 per wave)
#define NT 32                    // K/V tiles of 64 rows
#define NKEEP 614                // int(2048 * (1.0 - 0.7))
#define ATTN_SCALE 0.17677669529663688f  // 32^-0.5

// -------------------------------------------------------------------------
// GEMM: C[M][Nt] = A[M][K] @ W[Nt][K]^T + bias[Nt]   (unchanged, validated)
// -------------------------------------------------------------------------
__global__ __launch_bounds__(256) void gemm_nt_bias(
    const float* __restrict__ A, const float* __restrict__ W,
    const float* __restrict__ bias, float* __restrict__ C,
    int M, int Nt, int K)
{
    __shared__ __align__(16) float As[32][68];
    __shared__ __align__(16) float Ws[32][68];
    const int tid = threadIdx.x;
    const int bm = blockIdx.x * 64;
    const int bn = blockIdx.y * 64;
    const int tm = tid >> 4;
    const int tn = tid & 15;
    const int lr = tid >> 2;
    const int lq = tid & 3;
    const float* Ap = A + (size_t)(bm + lr) * K + lq * 8;
    const float* Wp = W + (size_t)(bn + lr) * K + lq * 8;
    float acc[4][4] = {};

    for (int k0 = 0; k0 < K; k0 += 32) {
        float4 a0 = *(const float4*)(Ap + k0);
        float4 a1 = *(const float4*)(Ap + k0 + 4);
        float4 w0 = *(const float4*)(Wp + k0);
        float4 w1 = *(const float4*)(Wp + k0 + 4);
        __syncthreads();
        const int kq = lq * 8;
        As[kq+0][lr]=a0.x; As[kq+1][lr]=a0.y; As[kq+2][lr]=a0.z; As[kq+3][lr]=a0.w;
        As[kq+4][lr]=a1.x; As[kq+5][lr]=a1.y; As[kq+6][lr]=a1.z; As[kq+7][lr]=a1.w;
        Ws[kq+0][lr]=w0.x; Ws[kq+1][lr]=w0.y; Ws[kq+2][lr]=w0.z; Ws[kq+3][lr]=w0.w;
        Ws[kq+4][lr]=w1.x; Ws[kq+5][lr]=w1.y; Ws[kq+6][lr]=w1.z; Ws[kq+7][lr]=w1.w;
        __syncthreads();
        #pragma unroll
        for (int k = 0; k < 32; ++k) {
            float4 av = *(const float4*)&As[k][tm*4];
            float4 wv = *(const float4*)&Ws[k][tn*4];
            acc[0][0] += av.x*wv.x; acc[0][1] += av.x*wv.y; acc[0][2] += av.x*wv.z; acc[0][3] += av.x*wv.w;
            acc[1][0] += av.y*wv.x; acc[1][1] += av.y*wv.y; acc[1][2] += av.y*wv.z; acc[1][3] += av.y*wv.w;
            acc[2][0] += av.z*wv.x; acc[2][1] += av.z*wv.y; acc[2][2] += av.z*wv.z; acc[2][3] += av.z*wv.w;
            acc[3][0] += av.w*wv.x; acc[3][1] += av.w*wv.y; acc[3][2] += av.w*wv.z; acc[3][3] += av.w*wv.w;
        }
    }
    float4 bb = *(const float4*)(bias + bn + tn*4);
    #pragma unroll
    for (int i = 0; i < 4; ++i) {
        float4 o;
        o.x = acc[i][0] + bb.x;
        o.y = acc[i][1] + bb.y;
        o.z = acc[i][2] + bb.z;
        o.w = acc[i][3] + bb.w;
        *(float4*)(C + (size_t)(bm + tm*4 + i) * Nt + bn + tn*4) = o;
    }
}

// -------------------------------------------------------------------------
// Fused sparse attention. QB=4 rows/block, 1 row per wave. Scores in LDS.
// Lane l: part p=l&3 (8-dim chunk), group jg=l>>2; thread's tile-col
// jloc = w*16+jg. K-dim split across 4-lane groups -> each K/V row's 128B
// read once per BLOCK. Radix select is barrier-free (hist row per wave).
// -------------------------------------------------------------------------
__device__ __forceinline__ unsigned int f2key(float f) {
    unsigned int u = __float_as_uint(f);
    return (u & 0x80000000u) ? ~u : (u | 0x80000000u);  // monotone order-preserving
}

typedef __attribute__((address_space(1))) const void gas_void;
typedef __attribute__((address_space(3))) void las_void;

__device__ __forceinline__ void gload_lds16(const float* g, float4* l) {
    __builtin_amdgcn_global_load_lds((gas_void*)g, (las_void*)l, 16, 0, 0);
}

// stage 64 rows x 32 floats (global row stride 768) into dst4[512].
// LDS slot u holds global chunk ((u&7) ^ (row&7)): XOR swizzle via source,
// LDS side stays lane-linear as global_load_lds requires.
__device__ __forceinline__ void stage64(const float* __restrict__ g, float4* dst4, int tid) {
    const int s0 = tid, s1 = tid + 256;
    const int r0 = s0 >> 3, c0 = (s0 & 7) ^ (r0 & 7);
    const int r1 = s1 >> 3, c1 = (s1 & 7) ^ (r1 & 7);
    gload_lds16(g + (size_t)r0 * 768 + c0 * 4, dst4 + s0);
    gload_lds16(g + (size_t)r1 * 768 + c1 * 4, dst4 + s1);
}

// raw barrier: drain LDS ops, do NOT drain vmcnt (keeps prefetch in flight)
#define RBAR() do { asm volatile("s_waitcnt lgkmcnt(0)" ::: "memory"); \
                    __builtin_amdgcn_s_barrier();                      \
                    asm volatile("" ::: "memory"); } while (0)
#define LGKM0() asm volatile("s_waitcnt lgkmcnt(0)" ::: "memory")
#define VM0()   asm volatile("s_waitcnt vmcnt(0)" ::: "memory")

__global__ __launch_bounds__(256, 3) void sparse_attn(
    const float* __restrict__ qkv, float* __restrict__ aout)
{
    __shared__ __align__(16) float4 kbuf[2][512];   // 16 KB ring; radix hist aliases kbuf[0]
    __shared__ __align__(16) float  sbuf[QB * NSEQ]; // 32 KB scores; PV partials alias it
    __shared__ unsigned int prefS[QB];
    __shared__ int   remS[QB];
    __shared__ float zS[QB];

    unsigned int* hist = (unsigned int*)&kbuf[0][0];  // [QB][256], radix phase only

    const int tid = threadIdx.x;
    const int w   = tid >> 6;       // wave id = row id (0..3)
    const int l   = tid & 63;
    const int p   = l & 3;          // dim-chunk (8 floats at 8p)
    const int jg  = l >> 2;         // 0..15
    const int jloc = w * 16 + jg;   // this thread's column within a 64-tile
    const int sw1 = (2 * p)     ^ (jloc & 7);
    const int sw2 = (2 * p + 1) ^ (jloc & 7);

    const int blk = blockIdx.x;
    const int nqb = NSEQ / QB;      // 512
    const int bh  = blk / nqb;
    const int qblk = blk % nqb;
    const int b = bh / NHEADS, h = bh % NHEADS;
    const int n0 = qblk * QB;

    const float* base = qkv + (size_t)b * NSEQ * 768;
    const float* gk = base + 256 + h * 32;
    const float* gv = base + 512 + h * 32;

    // ---- Q rows 0..3, this lane's 8-dim chunk, pre-scaled, in registers ----
    float4 qa[QB], qc[QB];
    {
        const float* gq = base + (size_t)n0 * 768 + h * 32 + p * 8;
        #pragma unroll
        for (int r = 0; r < QB; ++r) {
            float4 x0 = *(const float4*)(gq + (size_t)r * 768);
            float4 x1 = *(const float4*)(gq + (size_t)r * 768 + 4);
            qa[r].x = x0.x * ATTN_SCALE; qa[r].y = x0.y * ATTN_SCALE;
            qa[r].z = x0.z * ATTN_SCALE; qa[r].w = x0.w * ATTN_SCALE;
            qc[r].x = x1.x * ATTN_SCALE; qc[r].y = x1.y * ATTN_SCALE;
            qc[r].z = x1.z * ATTN_SCALE; qc[r].w = x1.w * ATTN_SCALE;
        }
    }
    if (tid < QB) { prefS[tid] = 0u; remS[tid] = NKEEP; }

    // ---- Phase B: scores. Each thread: 1 column per tile, 8-dim partial ----
    stage64(gk, &kbuf[0][0], tid);
    #pragma unroll 1
    for (int t = 0; t < NT; ++t) {
        VM0();     // my tile-t quarters landed
        RBAR();    // everyone's landed; everyone done reading tile t-1
        if (t + 1 < NT) stage64(gk + (size_t)(t + 1) * 64 * 768, &kbuf[(t + 1) & 1][0], tid);
        const float4* kb = &kbuf[t & 1][0];
        float4 k0 = kb[jloc * 8 + sw1];
        float4 k1 = kb[jloc * 8 + sw2];
        float sc0, sc1, sc2, sc3;
        {
            sc0 = qa[0].x*k0.x + qa[0].y*k0.y + qa[0].z*k0.z + qa[0].w*k0.w
                + qc[0].x*k1.x + qc[0].y*k1.y + qc[0].z*k1.z + qc[0].w*k1.w;
            sc1 = qa[1].x*k0.x + qa[1].y*k0.y + qa[1].z*k0.z + qa[1].w*k0.w
                + qc[1].x*k1.x + qc[1].y*k1.y + qc[1].z*k1.z + qc[1].w*k1.w;
            sc2 = qa[2].x*k0.x + qa[2].y*k0.y + qa[2].z*k0.z + qa[2].w*k0.w
                + qc[2].x*k1.x + qc[2].y*k1.y + qc[2].z*k1.z + qc[2].w*k1.w;
            sc3 = qa[3].x*k0.x + qa[3].y*k0.y + qa[3].z*k0.z + qa[3].w*k0.w
                + qc[3].x*k1.x + qc[3].y*k1.y + qc[3].z*k1.z + qc[3].w*k1.w;
        }
        // reduce the 4 dim-chunks within each 4-lane group
        sc0 += __shfl_xor(sc0, 1); sc0 += __shfl_xor(sc0, 2);
        sc1 += __shfl_xor(sc1, 1); sc1 += __shfl_xor(sc1, 2);
        sc2 += __shfl_xor(sc2, 1); sc2 += __shfl_xor(sc2, 2);
        sc3 += __shfl_xor(sc3, 1); sc3 += __shfl_xor(sc3, 2);
        // lane with part p writes row p's score for column t*64+jloc
        float myv = (p == 0) ? sc0 : (p == 1) ? sc1 : (p == 2) ? sc2 : sc3;
        sbuf[p * NSEQ + t * 64 + jloc] = myv;
    }
    RBAR();   // scores complete & visible; ring free (hist aliases kbuf[0])

    // ---- Phase C: exact 614th-largest per row. Wave w owns row w.       ----
    // hist row w touched ONLY by wave w -> no barriers, lgkm ordering only.
    unsigned int* hrow = hist + w * 256;
    #pragma unroll 1
    for (int pass = 3; pass >= 0; --pass) {
        uint4 z4; z4.x = 0u; z4.y = 0u; z4.z = 0u; z4.w = 0u;
        *(uint4*)(hrow + l * 4) = z4;
        LGKM0();
        const int sh = pass * 8;
        const unsigned int hmsk = (pass == 3) ? 0u : (0xFFFFFFFFu << (sh + 8));
        const unsigned int pr = prefS[w];
        const int remv = remS[w];
        #pragma unroll 1
        for (int e = 0; e < 32; ++e) {
            float f = sbuf[w * NSEQ + l + 64 * e];
            unsigned int key = f2key(f);
            if ((key & hmsk) == pr) atomicAdd(&hrow[(key >> sh) & 255u], 1u);
        }
        LGKM0();
        uint4 c4 = *(uint4*)(hrow + l * 4);
        unsigned int cnt[4] = { c4.x, c4.y, c4.z, c4.w };
        unsigned int part = cnt[0] + cnt[1] + cnt[2] + cnt[3];
        unsigned int suf = part;
        #pragma unroll
        for (int dlt = 1; dlt < 64; dlt <<= 1) {
            unsigned int v = __shfl_down(suf, dlt);
            if (l + dlt < 64) suf += v;
        }
        unsigned int run = suf - part;   // elems in bins owned by lanes > l
        #pragma unroll
        for (int i = 3; i >= 0; --i) {
            if ((int)run < remv && remv <= (int)(run + cnt[i])) {
                remS[w]  = remv - (int)run;
                prefS[w] = pr | ((unsigned int)(l * 4 + i) << sh);
            }
            run += cnt[i];
        }
        LGKM0();  // pref/rem visible wave-wide before next pass
    }
    RBAR();   // all waves done with hist region; ring reusable for V

    // V tile 0 prefetch flies across the whole softmax phase
    stage64(gv, &kbuf[0][0], tid);

    // ---- Phase D: masked softmax on row w (in LDS) ----
    {
        unsigned int key = prefS[w];
        unsigned int u = (key & 0x80000000u) ? (key & 0x7FFFFFFFu) : ~key;
        const float thr = __uint_as_float(u);
        float mx = 0.f;   // >=1434 masked zeros always present
        #pragma unroll 1
        for (int e = 0; e < 32; ++e) {
            int idx = w * NSEQ + l + 64 * e;
            float f = sbuf[idx];
            float mv = (f >= thr) ? f : 0.f;
            sbuf[idx] = mv;
            mx = fmaxf(mx, mv);
        }
        #pragma unroll
        for (int d2 = 32; d2 >= 1; d2 >>= 1) mx = fmaxf(mx, __shfl_xor(mx, d2));
        float Z = 0.f;
        #pragma unroll 1
        for (int e = 0; e < 32; ++e) {
            int idx = w * NSEQ + l + 64 * e;
            float pe = __expf(sbuf[idx] - mx);
            sbuf[idx] = pe;
            Z += pe;
        }
        #pragma unroll
        for (int d2 = 32; d2 >= 1; d2 >>= 1) Z += __shfl_xor(Z, d2);
        if (l == 0) zS[w] = Z;
    }
    RBAR();   // p-values of all rows visible to all waves

    // ---- Phase E: PV. Thread: 1 column per tile, 8-dim chunk of output ----
    float4 oa0, oa1, oa2, oa3, ob0, ob1, ob2, ob3;
    oa0.x=0;oa0.y=0;oa0.z=0;oa0.w=0; ob0=oa0; oa1=oa0; ob1=oa0;
    oa2=oa0; ob2=oa0; oa3=oa0; ob3=oa0;
    #pragma unroll 1
    for (int t = 0; t < NT; ++t) {
        VM0();
        RBAR();
        if (t + 1 < NT) stage64(gv + (size_t)(t + 1) * 64 * 768, &kbuf[(t + 1) & 1][0], tid);
        const float4* vb = &kbuf[t & 1][0];
        float4 v0 = vb[jloc * 8 + sw1];
        float4 v1 = vb[jloc * 8 + sw2];
        const int j = t * 64 + jloc;
        float p0 = sbuf[0 * NSEQ + j];
        float p1 = sbuf[1 * NSEQ + j];
        float p2 = sbuf[2 * NSEQ + j];
        float p3 = sbuf[3 * NSEQ + j];
        oa0.x=fmaf(p0,v0.x,oa0.x); oa0.y=fmaf(p0,v0.y,oa0.y); oa0.z=fmaf(p0,v0.z,oa0.z); oa0.w=fmaf(p0,v0.w,oa0.w);
        ob0.x=fmaf(p0,v1.x,ob0.x); ob0.y=fmaf(p0,v1.y,ob0.y); ob0.z=fmaf(p0,v1.z,ob0.z); ob0.w=fmaf(p0,v1.w,ob0.w);
        oa1.x=fmaf(p1,v0.x,oa1.x); oa1.y=fmaf(p1,v0.y,oa1.y); oa1.z=fmaf(p1,v0.z,oa1.z); oa1.w=fmaf(p1,v0.w,oa1.w);
        ob1.x=fmaf(p1,v1.x,ob1.x); ob1.y=fmaf(p1,v1.y,ob1.y); ob1.z=fmaf(p1,v1.z,ob1.z); ob1.w=fmaf(p1,v1.w,ob1.w);
        oa2.x=fmaf(p2,v0.x,oa2.x); oa2.y=fmaf(p2,v0.y,oa2.y); oa2.z=fmaf(p2,v0.z,oa2.z); oa2.w=fmaf(p2,v0.w,oa2.w);
        ob2.x=fmaf(p2,v1.x,ob2.x); ob2.y=fmaf(p2,v1.y,ob2.y); ob2.z=fmaf(p2,v1.z,ob2.z); ob2.w=fmaf(p2,v1.w,ob2.w);
        oa3.x=fmaf(p3,v0.x,oa3.x); oa3.y=fmaf(p3,v0.y,oa3.y); oa3.z=fmaf(p3,v0.z,oa3.z); oa3.w=fmaf(p3,v0.w,oa3.w);
        ob3.x=fmaf(p3,v1.x,ob3.x); ob3.y=fmaf(p3,v1.y,ob3.y); ob3.z=fmaf(p3,v1.z,ob3.z); ob3.w=fmaf(p3,v1.w,ob3.w);
    }
    RBAR();   // all p reads done; sbuf reusable as partial buffer

    // reduce over the 16 column-groups (lanes differing in bits 2..5)
    #pragma unroll
    for (int d2 = 4; d2 <= 32; d2 <<= 1) {
        oa0.x+=__shfl_xor(oa0.x,d2); oa0.y+=__shfl_xor(oa0.y,d2); oa0.z+=__shfl_xor(oa0.z,d2); oa0.w+=__shfl_xor(oa0.w,d2);
        ob0.x+=__shfl_xor(ob0.x,d2); ob0.y+=__shfl_xor(ob0.y,d2); ob0.z+=__shfl_xor(ob0.z,d2); ob0.w+=__shfl_xor(ob0.w,d2);
        oa1.x+=__shfl_xor(oa1.x,d2); oa1.y+=__shfl_xor(oa1.y,d2); oa1.z+=__shfl_xor(oa1.z,d2); oa1.w+=__shfl_xor(oa1.w,d2);
        ob1.x+=__shfl_xor(ob1.x,d2); ob1.y+=__shfl_xor(ob1.y,d2); ob1.z+=__shfl_xor(ob1.z,d2); ob1.w+=__shfl_xor(ob1.w,d2);
        oa2.x+=__shfl_xor(oa2.x,d2); oa2.y+=__shfl_xor(oa2.y,d2); oa2.z+=__shfl_xor(oa2.z,d2); oa2.w+=__shfl_xor(oa2.w,d2);
        ob2.x+=__shfl_xor(ob2.x,d2); ob2.y+=__shfl_xor(ob2.y,d2); ob2.z+=__shfl_xor(ob2.z,d2); ob2.w+=__shfl_xor(ob2.w,d2);
        oa3.x+=__shfl_xor(oa3.x,d2); oa3.y+=__shfl_xor(oa3.y,d2); oa3.z+=__shfl_xor(oa3.z,d2); oa3.w+=__shfl_xor(oa3.w,d2);
        ob3.x+=__shfl_xor(ob3.x,d2); ob3.y+=__shfl_xor(ob3.y,d2); ob3.z+=__shfl_xor(ob3.z,d2); ob3.w+=__shfl_xor(ob3.w,d2);
    }
    // lanes 0..3 of each wave hold dim-chunk l for all 4 rows
    if (l < 4) {
        float* part = &sbuf[0];   // [4 waves][4 rows][32 dims]
        *(float4*)&part[(w * 4 + 0) * 32 + l * 8]     = oa0;
        *(float4*)&part[(w * 4 + 0) * 32 + l * 8 + 4] = ob0;
        *(float4*)&part[(w * 4 + 1) * 32 + l * 8]     = oa1;
        *(float4*)&part[(w * 4 + 1) * 32 + l * 8 + 4] = ob1;
        *(float4*)&part[(w * 4 + 2) * 32 + l * 8]     = oa2;
        *(float4*)&part[(w * 4 + 2) * 32 + l * 8 + 4] = ob2;
        *(float4*)&part[(w * 4 + 3) * 32 + l * 8]     = oa3;
        *(float4*)&part[(w * 4 + 3) * 32 + l * 8 + 4] = ob3;
    }
    RBAR();
    if (tid < 128) {
        const int r = tid >> 5, d = tid & 31;
        const float* part = &sbuf[0];
        float o = part[(0 * 4 + r) * 32 + d] + part[(1 * 4 + r) * 32 + d]
                + part[(2 * 4 + r) * 32 + d] + part[(3 * 4 + r) * 32 + d];
        o /= zS[r];
        aout[((size_t)b * NSEQ + n0 + r) * CDIM + h * 32 + d] = o;
    }
}

// -------------------------------------------------------------------------
extern "C" void kernel_launch(void* const* d_in, const int* in_sizes, int n_in,
                              void* d_out, int out_size, void* d_ws, size_t ws_size,
                              hipStream_t stream) {
    (void)in_sizes; (void)n_in; (void)out_size; (void)ws_size;
    const float* x      = (const float*)d_in[0];
    const float* w_qkv  = (const float*)d_in[1];
    const float* b_qkv  = (const float*)d_in[2];
    const float* w_proj = (const float*)d_in[3];
    const float* b_proj = (const float*)d_in[4];
    float* out = (float*)d_out;

    const int M = BDIM * NSEQ;  // 8192
    float* qkv_ws  = (float*)d_ws;                       // 25.2 MB
    float* attn_ws = qkv_ws + (size_t)M * 768;           // 8.4 MB

    // 1) QKV GEMM -> [B][N][3][H][D]
    dim3 g1(M / 64, 768 / 64);
    gemm_nt_bias<<<g1, 256, 0, stream>>>(x, w_qkv, b_qkv, qkv_ws, M, 768, 256);

    // 2) fused sparse attention -> [B][N][C]
    sparse_attn<<<BDIM * NHEADS * (NSEQ / QB), 256, 0, stream>>>(qkv_ws, attn_ws);

    // 3) projection GEMM -> d_out
    dim3 g2(M / 64, 256 / 64);
    gemm_nt_bias<<<g2, 256, 0, stream>>>(attn_ws, w_proj, b_proj, out, M, 256, 256);
}